// Round 3
// baseline (329.195 us; speedup 1.0000x reference)
//
#include <hip/hip_runtime.h>

// g2[b,c,h,w] = sum_d cost[b,d,h,w] * h1[b,c,h,w+d]   (w+d < W, else 0)
// B=4 C=32 H=256 W=512 D=48, fp32.
//
// v4: LDS-pipe pressure was the v3 limiter (8 ds_read_b128/wave/group =
// 3x oversubscription of the shared LDS pipe vs VALU; bank-conflict
// counter ~22cy/read since wave64 b128 puts 8 lanes on every bank).
// Fix: register sliding window (1 ds_read per channel per group) sized
// UNDER the 64-VGPR cliff that sank v1/v2:
//   - NT=512 = 8 waves, 2 channels per wave, CHB=16 channels per block.
//     Loop-carried: win[2][8]=16 + acc[2][4]=8 + cv[4][4]=16 + addr ~55.
//   - LDS 19968 B -> 4 blocks/CU x 8 waves = 32 waves/CU retained.
//   - compute ds_read_b128 total drops 1.57M -> 0.92M.
//   - all 8 waves load identical cost quads -> followers L1/L2-hit,
//     staggering the vmcnt chains.

#define BB 4
#define CC 32
#define CHB 16           // channels per block
#define HH 256
#define WW 512
#define DDISP 48
#define HW (HH * WW)     // 131072
#define TW 256
#define WROW 312         // 308 needed (TW + 44 + 7 + quad-round) + pad
#define NT 512

__global__ __launch_bounds__(NT, 8)
void dense_warp_kernel(const float* __restrict__ h1,
                       const float* __restrict__ cost,
                       float* __restrict__ out)
{
    __shared__ float h1s[CHB * WROW];   // 19968 B

    const int blk    = blockIdx.x;
    const int wside  = blk & 1;
    const int h      = (blk >> 1) & (HH - 1);
    const int chalf  = (blk >> 9) & 1;
    const int b      = blk >> 10;
    const int wstart = wside * TW;
    const int tid    = threadIdx.x;

    // ---- stage h1[b, chalf*16 .. +15, h, wstart .. wstart+311] (zeros past W)
    {
        const float* src = h1 + (((size_t)b * CC + chalf * CHB) * HH + (size_t)h) * WW;
        for (int idx = tid; idx < CHB * 78; idx += NT) {   // 78 quads/row
            int r    = idx / 78;
            int q    = idx - r * 78;
            int col  = q << 2;
            int wsrc = wstart + col;
            float4 v = make_float4(0.f, 0.f, 0.f, 0.f);
            if (wsrc < WW) v = *(const float4*)(src + (size_t)r * HW + wsrc);
            *(float4*)(&h1s[r * WROW + col]) = v;
        }
    }
    __syncthreads();

    const int lane = tid & 63;
    const int wid  = tid >> 6;        // 0..7 -> channel pair
    const int c0   = wid << 1;        // 2 channels per wave
    const int w0   = lane << 2;       // 4 consecutive w per lane

    float acc[2][4];
#pragma unroll
    for (int c = 0; c < 2; ++c)
#pragma unroll
        for (int j = 0; j < 4; ++j) acc[c][j] = 0.f;

    // win[c][slot*4+k]: circular 2-quad window. Invariant at start of group g:
    // slot (g&1) = h1 quad at w0+4g, slot ((g+1)&1) = quad at w0+4g+4.
    float win[2][8];
    const float* lptr = &h1s[c0 * WROW + w0];   // advances 4 floats per group
#pragma unroll
    for (int c = 0; c < 2; ++c) {
        float4 q0 = *(const float4*)(lptr + c * WROW);
        float4 q1 = *(const float4*)(lptr + c * WROW + 4);
        win[c][0] = q0.x; win[c][1] = q0.y; win[c][2] = q0.z; win[c][3] = q0.w;
        win[c][4] = q1.x; win[c][5] = q1.y; win[c][6] = q1.z; win[c][7] = q1.w;
    }

    const float* cp = cost + ((size_t)b * DDISP * HH + (size_t)h) * WW + wstart + w0;

    float cv[4][4];

    // Group g covers d = 4g..4g+3; output j needs operand w0+4g+(dd+j),
    // dd+j in 0..6 -> the 2-quad window [4g, 4g+7].
#pragma unroll
    for (int g = 0; g < 12; ++g) {
        const int P = g & 1;   // static after unroll
#pragma unroll
        for (int dd = 0; dd < 4; ++dd) {
            float4 t = *(const float4*)(cp + (size_t)(4 * g + dd) * HW);
            cv[dd][0] = t.x; cv[dd][1] = t.y; cv[dd][2] = t.z; cv[dd][3] = t.w;
        }
#pragma unroll
        for (int c = 0; c < 2; ++c) {
#pragma unroll
            for (int dd = 0; dd < 4; ++dd)
#pragma unroll
                for (int j = 0; j < 4; ++j) {
                    const int o    = dd + j;              // 0..6
                    const int slot = (P + (o >> 2)) & 1;
                    acc[c][j] += cv[dd][j] * win[c][slot * 4 + (o & 3)];
                }
            // slide: replace oldest quad (slot P) with quad g+2
            float4 t = *(const float4*)(lptr + c * WROW + 8);
            win[c][P * 4 + 0] = t.x; win[c][P * 4 + 1] = t.y;
            win[c][P * 4 + 2] = t.z; win[c][P * 4 + 3] = t.w;
        }
        lptr += 4;
    }

    float* outBase = out + (((size_t)b * CC + chalf * CHB) * HH + (size_t)h) * WW
                     + wstart + w0;
#pragma unroll
    for (int c = 0; c < 2; ++c) {
        float* op = outBase + (size_t)(c0 + c) * HW;
        *(float4*)op = make_float4(acc[c][0], acc[c][1], acc[c][2], acc[c][3]);
    }
}

extern "C" void kernel_launch(void* const* d_in, const int* in_sizes, int n_in,
                              void* d_out, int out_size, void* d_ws, size_t ws_size,
                              hipStream_t stream) {
    const float* h1   = (const float*)d_in[0];
    const float* cost = (const float*)d_in[1];
    float* out        = (float*)d_out;
    dim3 grid(BB * HH * 2 * 2);   // (b, chalf, h, w-half)
    dense_warp_kernel<<<grid, NT, 0, stream>>>(h1, cost, out);
}

// Round 4
// 248.713 us; speedup vs baseline: 1.3236x; 1.3236x over previous
//
#include <hip/hip_runtime.h>

// g2[b,c,h,w] = sum_d cost[b,d,h,w] * h1[b,c,h,w+d]   (w+d < W, else 0)
// B=4 C=32 H=256 W=512 D=48, fp32.
//
// v5 = v4 with the launch-bounds fix. History of the allocator on this
// kernel: min_waves_per_EU=4 -> 64 VGPR (v0/v1), min=8 -> 32 VGPR
// (v3/v4). v4's sliding window needs ~55 live regs; at 32 it spilled
// 237 MB of scratch (WRITE_SIZE 65.5->303 MB) and regressed 110->197us
// even though its LDS-read halving worked (conflict cycles -37%).
// Fix: __launch_bounds__(512, 4) -> 64-VGPR allocation, zero spill.
// HW occupancy unchanged: min(LDS 8 blocks, VGPR 512/64=8 waves/EU)
// = 32 waves/CU.
//
// Structure (unchanged from v4):
//   - NT=512 = 8 waves, 2 channels per wave, CHB=16 channels per block.
//   - register sliding window: 1 ds_read_b128 per channel per group
//     (half of v3's LDS traffic, which was the v3 limiter).
//   - all 8 waves load identical cost quads -> followers hit L1/L2.

#define BB 4
#define CC 32
#define CHB 16           // channels per block
#define HH 256
#define WW 512
#define DDISP 48
#define HW (HH * WW)     // 131072
#define TW 256
#define WROW 312         // 308 needed (TW + 44 + 7 + quad-round) + pad
#define NT 512

__global__ __launch_bounds__(NT, 4)
void dense_warp_kernel(const float* __restrict__ h1,
                       const float* __restrict__ cost,
                       float* __restrict__ out)
{
    __shared__ float h1s[CHB * WROW];   // 19968 B

    const int blk    = blockIdx.x;
    const int wside  = blk & 1;
    const int h      = (blk >> 1) & (HH - 1);
    const int chalf  = (blk >> 9) & 1;
    const int b      = blk >> 10;
    const int wstart = wside * TW;
    const int tid    = threadIdx.x;

    // ---- stage h1[b, chalf*16 .. +15, h, wstart .. wstart+311] (zeros past W)
    {
        const float* src = h1 + (((size_t)b * CC + chalf * CHB) * HH + (size_t)h) * WW;
        for (int idx = tid; idx < CHB * 78; idx += NT) {   // 78 quads/row
            int r    = idx / 78;
            int q    = idx - r * 78;
            int col  = q << 2;
            int wsrc = wstart + col;
            float4 v = make_float4(0.f, 0.f, 0.f, 0.f);
            if (wsrc < WW) v = *(const float4*)(src + (size_t)r * HW + wsrc);
            *(float4*)(&h1s[r * WROW + col]) = v;
        }
    }
    __syncthreads();

    const int lane = tid & 63;
    const int wid  = tid >> 6;        // 0..7 -> channel pair
    const int c0   = wid << 1;        // 2 channels per wave
    const int w0   = lane << 2;       // 4 consecutive w per lane

    float acc[2][4];
#pragma unroll
    for (int c = 0; c < 2; ++c)
#pragma unroll
        for (int j = 0; j < 4; ++j) acc[c][j] = 0.f;

    // win[c][slot*4+k]: circular 2-quad window. Invariant at start of group g:
    // slot (g&1) = h1 quad at w0+4g, slot ((g+1)&1) = quad at w0+4g+4.
    float win[2][8];
    const float* lptr = &h1s[c0 * WROW + w0];   // advances 4 floats per group
#pragma unroll
    for (int c = 0; c < 2; ++c) {
        float4 q0 = *(const float4*)(lptr + c * WROW);
        float4 q1 = *(const float4*)(lptr + c * WROW + 4);
        win[c][0] = q0.x; win[c][1] = q0.y; win[c][2] = q0.z; win[c][3] = q0.w;
        win[c][4] = q1.x; win[c][5] = q1.y; win[c][6] = q1.z; win[c][7] = q1.w;
    }

    const float* cp = cost + ((size_t)b * DDISP * HH + (size_t)h) * WW + wstart + w0;

    float cv[4][4];

    // Group g covers d = 4g..4g+3; output j needs operand w0+4g+(dd+j),
    // dd+j in 0..6 -> the 2-quad window [4g, 4g+7].
#pragma unroll
    for (int g = 0; g < 12; ++g) {
        const int P = g & 1;   // static after unroll
#pragma unroll
        for (int dd = 0; dd < 4; ++dd) {
            float4 t = *(const float4*)(cp + (size_t)(4 * g + dd) * HW);
            cv[dd][0] = t.x; cv[dd][1] = t.y; cv[dd][2] = t.z; cv[dd][3] = t.w;
        }
#pragma unroll
        for (int c = 0; c < 2; ++c) {
#pragma unroll
            for (int dd = 0; dd < 4; ++dd)
#pragma unroll
                for (int j = 0; j < 4; ++j) {
                    const int o    = dd + j;              // 0..6
                    const int slot = (P + (o >> 2)) & 1;
                    acc[c][j] += cv[dd][j] * win[c][slot * 4 + (o & 3)];
                }
            // slide: replace oldest quad (slot P) with quad g+2
            float4 t = *(const float4*)(lptr + c * WROW + 8);
            win[c][P * 4 + 0] = t.x; win[c][P * 4 + 1] = t.y;
            win[c][P * 4 + 2] = t.z; win[c][P * 4 + 3] = t.w;
        }
        lptr += 4;
    }

    float* outBase = out + (((size_t)b * CC + chalf * CHB) * HH + (size_t)h) * WW
                     + wstart + w0;
#pragma unroll
    for (int c = 0; c < 2; ++c) {
        float* op = outBase + (size_t)(c0 + c) * HW;
        *(float4*)op = make_float4(acc[c][0], acc[c][1], acc[c][2], acc[c][3]);
    }
}

extern "C" void kernel_launch(void* const* d_in, const int* in_sizes, int n_in,
                              void* d_out, int out_size, void* d_ws, size_t ws_size,
                              hipStream_t stream) {
    const float* h1   = (const float*)d_in[0];
    const float* cost = (const float*)d_in[1];
    float* out        = (float*)d_out;
    dim3 grid(BB * HH * 2 * 2);   // (b, chalf, h, w-half)
    dense_warp_kernel<<<grid, NT, 0, stream>>>(h1, cost, out);
}